// Round 15
// baseline (921.853 us; speedup 1.0000x reference)
//
#include <hip/hip_runtime.h>
#include <hip/hip_fp16.h>

typedef unsigned int u32;
typedef _Float16 h2f __attribute__((ext_vector_type(2)));
typedef _Float16 f16x8 __attribute__((ext_vector_type(8)));
typedef float f32x4 __attribute__((ext_vector_type(4)));

#define BB 128
#define TT 512
#define DD 64
#define NBL 32
#define GIN 2080

// DPP: quad_perm xor1=0xB1 xor2=0x4E xor3=0x1B; half_mirror(rev8)=0x141;
// row_mirror(rev16)=0x140. All VALU-pipe.
template <int CTRL>
__device__ __forceinline__ float dpp_mov_f(float x) {
  return __builtin_bit_cast(
      float, __builtin_amdgcn_update_dpp(0, __builtin_bit_cast(int, x), CTRL,
                                         0xF, 0xF, true));
}
template <int CTRL>
__device__ __forceinline__ float dpp_add_f(float x) {
  return x + dpp_mov_f<CTRL>(x);
}
__device__ __forceinline__ float4 dpp_mov_f4_x1(float4 v) {
  return make_float4(dpp_mov_f<0xB1>(v.x), dpp_mov_f<0xB1>(v.y),
                     dpp_mov_f<0xB1>(v.z), dpp_mov_f<0xB1>(v.w));
}
__device__ __forceinline__ float swz_add16(float x) {  // xor16 within 32
  return x + __builtin_bit_cast(float, __builtin_amdgcn_ds_swizzle(
                                           __builtin_bit_cast(int, x), 0x401F));
}
__device__ __forceinline__ float bpermf(int addr, float x) {
  return __builtin_bit_cast(
      float, __builtin_amdgcn_ds_bpermute(addr, __builtin_bit_cast(int, x)));
}
__device__ __forceinline__ float xorf(float a, u32 m) {
  return __builtin_bit_cast(float, __builtin_bit_cast(u32, a) ^ m);
}
__device__ __forceinline__ float uni_f(float v) {
  return __builtin_bit_cast(
      float, __builtin_amdgcn_readfirstlane(__builtin_bit_cast(int, v)));
}
__device__ __forceinline__ int uni_i(int v) {
  return __builtin_amdgcn_readfirstlane(v);
}

// sign of e_i * e_j in Cl(4,1): 1 if negative
__device__ inline int gp_negbit(int i, int j) {
  int sw = 0;
#pragma unroll
  for (int b = 0; b < 5; ++b)
    if ((j >> b) & 1) sw += __popc(i >> (b + 1));
  return (sw ^ ((i & j) >> 4)) & 1;  // METRIC[4] = -1
}

__device__ inline u32 pkf16(float a, float b) {
  return __builtin_bit_cast(u32, __builtin_amdgcn_cvt_pkrtz(a, b));
}

// GP quad-term (R10/R12-verified signs). RN = the SGPR-resident raw emb row
// array — passed explicitly so macro substitution reaches this body.
#define GPQ(Q, E, RN)                                            \
  do {                                                           \
    float t0 = xorf(RN[(Q)], sb[(Q)]);                           \
    float t1 = xorf(RN[(Q) + 8], sb[(Q) + 8]);                   \
    float t2 = xorf(RN[(Q) + 16], sb[(Q) + 16]);                 \
    float t3 = xorf(RN[(Q) + 24], sb[(Q) + 24]);                 \
    b0 = fmaf(t0, (E).x, b0);                                    \
    b1v = fmaf(t0, (E).y, b1v);                                  \
    b2v = fmaf(t0, (E).z, b2v);                                  \
    b3v = fmaf(t0, (E).w, b3v);                                  \
    b0 = fmaf(t1, (E).y, b0);                                    \
    b1v = fmaf(t1, (E).x, b1v);                                  \
    b2v = fmaf(t1, (E).w, b2v);                                  \
    b3v = fmaf(t1, (E).z, b3v);                                  \
    b0 = fmaf(t2, (E).z, b0);                                    \
    b1v = fmaf(-t2, (E).w, b1v);                                 \
    b2v = fmaf(-t2, (E).x, b2v);                                 \
    b3v = fmaf(t2, (E).y, b3v);                                  \
    b0 = fmaf(t3, (E).w, b0);                                    \
    b1v = fmaf(-t3, (E).z, b1v);                                 \
    b2v = fmaf(-t3, (E).y, b2v);                                 \
    b3v = fmaf(t3, (E).x, b3v);                                  \
  } while (0)

// One recurrence step. R14: gate matvec on the MFMA pipe.
// Wave w covers k-eighth [256w,256w+256) = its own 8 state rows as 8 chunks;
// 4 row-tiles of 16 gate rows each -> 32 v_mfma_f32_16x16x32_f16 per step.
// B is replicated across columns (all lanes read chunk dwords 4*(l>>4)+u, a
// broadcast b128), so EVERY lane's D holds rows 4*(l>>4)+reg of its tile.
// z-partials staged in zbuf[8][64], summed after barrier B.
#define STEP(P, RNR, XI)                                                      \
  do {                                                                        \
    const int pn = (P) ^ 1;                                                   \
    /* ---- gate partials via MFMA (A=weights in AGPR, B=h broadcast) ---- */ \
    f32x4 D0 = {0.f, 0.f, 0.f, 0.f};                                          \
    f32x4 D1 = {0.f, 0.f, 0.f, 0.f};                                          \
    f32x4 D2 = {0.f, 0.f, 0.f, 0.f};                                          \
    f32x4 D3 = {0.f, 0.f, 0.f, 0.f};                                          \
    _Pragma("unroll") for (int cc = 0; cc < 8; ++cc) {                        \
      uint4 bv = *(const uint4*)&h16b[(P)][136 * w + 17 * cc + (g4 << 2)];    \
      f16x8 bf = __builtin_bit_cast(f16x8, bv);                               \
      D0 = __builtin_amdgcn_mfma_f32_16x16x32_f16(gwa[0][cc], bf, D0, 0, 0, 0); \
      D1 = __builtin_amdgcn_mfma_f32_16x16x32_f16(gwa[1][cc], bf, D1, 0, 0, 0); \
      D2 = __builtin_amdgcn_mfma_f32_16x16x32_f16(gwa[2][cc], bf, D2, 0, 0, 0); \
      D3 = __builtin_amdgcn_mfma_f32_16x16x32_f16(gwa[3][cc], bf, D3, 0, 0, 0); \
    }                                                                         \
    /* ---- GP (R12-verified): 3 LDS reads + DPP xor1 pairs, f32 math ---- */ \
    float b0 = 0.f, b1v = 0.f, b2v = 0.f, b3v = 0.f;                          \
    {                                                                         \
      float4 hqe = make_float4(u0, u1, u2, u3);                               \
      float4 hqo = dpp_mov_f4_x1(hqe);                                        \
      GPQ(0, hqe, RNR);                                                       \
      GPQ(1, hqo, RNR);                                                       \
      hqe = *(const float4*)&h32[(P)][d][(2 ^ cq) << 2];                      \
      hqo = dpp_mov_f4_x1(hqe);                                               \
      GPQ(2, hqe, RNR);                                                       \
      GPQ(3, hqo, RNR);                                                       \
      hqe = *(const float4*)&h32[(P)][d][(4 ^ cq) << 2];                      \
      hqo = dpp_mov_f4_x1(hqe);                                               \
      GPQ(4, hqe, RNR);                                                       \
      GPQ(5, hqo, RNR);                                                       \
      hqe = *(const float4*)&h32[(P)][d][(6 ^ cq) << 2];                      \
      hqo = dpp_mov_f4_x1(hqe);                                               \
      GPQ(6, hqe, RNR);                                                       \
      GPQ(7, hqo, RNR);                                                       \
    }                                                                         \
    /* ---- stage z-partials: lane group (l&15)==t writes tile t ---- */      \
    if (c16 == 0) *(float4*)&zbuf[w][(g4 << 2)] =                             \
        make_float4(D0[0], D0[1], D0[2], D0[3]);                              \
    if (c16 == 1) *(float4*)&zbuf[w][16 + (g4 << 2)] =                        \
        make_float4(D1[0], D1[1], D1[2], D1[3]);                              \
    if (c16 == 2) *(float4*)&zbuf[w][32 + (g4 << 2)] =                        \
        make_float4(D2[0], D2[1], D2[2], D2[3]);                              \
    if (c16 == 3) *(float4*)&zbuf[w][48 + (g4 << 2)] =                        \
        make_float4(D3[0], D3[1], D3[2], D3[3]);                              \
    __syncthreads(); /* barrier B: z-partials visible */                      \
    float zv = zbuf[0][d] + zbuf[1][d] + zbuf[2][d] + zbuf[3][d] +            \
               zbuf[4][d] + zbuf[5][d] + zbuf[6][d] + zbuf[7][d];             \
    float rcsel = ((XI) == 0)   ? rcv0                                        \
                  : ((XI) == 1) ? rcv1                                        \
                  : ((XI) == 2) ? rcv2                                        \
                                : rcv3;                                       \
    float invsel = ((XI) == 0)   ? iv0                                        \
                   : ((XI) == 1) ? iv1                                        \
                   : ((XI) == 2) ? iv2                                        \
                                 : iv3;                                       \
    float g = 1.f / (1.f + exp2f(-1.44269504f * (zv + rcsel)));               \
    /* ---- gated update + mnorm over 8-lane group (R10-verified) ---- */     \
    float gi = g * invsel;                                                    \
    float om = 1.f - g;                                                       \
    float nu0 = fmaf(gi, b0, om * u0);                                        \
    float nu1 = fmaf(gi, b1v, om * u1);                                       \
    float nu2 = fmaf(gi, b2v, om * u2);                                       \
    float nu3 = fmaf(gi, b3v, om * u3);                                       \
    float sq = nu0 * nu0 + nu1 * nu1 + nu2 * nu2 + nu3 * nu3;                 \
    sq = dpp_add_f<0xB1>(sq);                                                 \
    sq = dpp_add_f<0x4E>(sq);                                                 \
    sq = dpp_add_f<0x141>(sq);                                                \
    float sc = 1.f / (sqrtf(sq) + 1e-8f);                                     \
    u0 = nu0 * sc; u1 = nu1 * sc; u2 = nu2 * sc; u3 = nu3 * sc;               \
    *(float4*)&h32[pn][d][cq << 2] = make_float4(u0, u1, u2, u3);             \
    float v0 = dpp_mov_f<0xB1>(u0);                                           \
    float v1 = dpp_mov_f<0xB1>(u1);                                           \
    float v2 = dpp_mov_f<0xB1>(u2);                                           \
    float v3 = dpp_mov_f<0xB1>(u3);                                           \
    if (!(l & 1)) { /* even cq packs blade pairs (cq,cq+1) etc. */            \
      h16b[pn][17 * d + (cq >> 1)] = pkf16(u0, v0);                           \
      h16b[pn][17 * d + (cq >> 1) + 4] = pkf16(u1, v1);                       \
      h16b[pn][17 * d + (cq >> 1) + 8] = pkf16(u2, v2);                       \
      h16b[pn][17 * d + (cq >> 1) + 12] = pkf16(u3, v3);                      \
    }                                                                         \
    __syncthreads(); /* barrier A: state for next step visible */             \
  } while (0)

__global__ __launch_bounds__(512, 2) void versor_fused(
    const int* __restrict__ x, const float* __restrict__ emb,
    const float* __restrict__ gate_w, const float* __restrict__ gate_b,
    const float* __restrict__ w1, const float* __restrict__ b1g,
    const float* __restrict__ ln_g, const float* __restrict__ ln_b,
    const float* __restrict__ w2, const float* __restrict__ b2,
    float* __restrict__ out) {
  __shared__ float rn[4][NBL];   // normalized emb rows (init/rc only)
  __shared__ float inv_lds[4];   // 1/(||emb_row||+eps)
  __shared__ float rc[4][DD];    // r-part of gate, pre-dotted
  __shared__ __align__(16) float h32[2][DD][36];  // fp32 h, owner-quad-major
  __shared__ __align__(16) u32 h16b[2][1088];     // f16x2 h, row-major s17
  __shared__ float zbuf[8][DD];                   // gate z partials per wave
  __shared__ __align__(16) float hs[2048];        // final h for head
  __shared__ float redA[8][2];
  __shared__ float redB[8][2];

  const int b = blockIdx.x;
  const int tid = threadIdx.x;
  const int w = tid >> 6;       // wave 0..7 (k-eighth)
  const int l = tid & 63;       // lane
  const int rl = l >> 3;        // 0..7
  const int d = (w << 3) + rl;  // this lane's state row
  const int cq = l & 7;         // GP owner quad: blades {cq,cq+8,cq+16,cq+24}
  const int c16 = l & 15;       // MFMA column / A-row-in-tile
  const int g4 = l >> 4;        // MFMA k-slice group 0..3
  const int bp32 = ((l ^ 32) << 2);

  // ---- init: normalized embeddings + inverse norms ----
  if (tid < 4) {
    float v[NBL];
    float sum = 0.f;
    for (int i = 0; i < NBL; ++i) {
      v[i] = emb[tid * NBL + i];
      sum += v[i] * v[i];
    }
    float sc = 1.f / (sqrtf(sum) + 1e-8f);
    inv_lds[tid] = sc;
    for (int i = 0; i < NBL; ++i) rn[tid][i] = v[i] * sc;
  }
  for (int idx = tid; idx < DD * 36; idx += 512) {
    int dd = idx / 36, jj = idx - dd * 36;
    h32[0][dd][jj] = (jj == 0) ? 1.f : 0.f;  // e0: owner 0, slot 0
  }
  for (int idx = tid; idx < 1088; idx += 512) {
    int jj = idx - (idx / 17) * 17;
    h16b[0][idx] = (jj == 0) ? 0x00003C00u : 0u;  // row pair0 = (1.0h, 0)
  }
  __syncthreads();

  // ---- rc[e][row] = sum_i gate_w[row][2048+i] * rn_normalized[e][i] ----
  if (tid < 256) {
    int e = tid >> 6, row = tid & 63;
    float sum = 0.f;
    for (int i = 0; i < NBL; ++i) sum += gate_w[row * GIN + 2048 + i] * rn[e][i];
    rc[e][row] = sum;
  }

  // ---- gate weights -> MFMA A-fragments (f16), AGPR-resident ----
  // tile t rows [16t,16t+16): lane holds A[c16][k], k = 256w+32cc+8*g4+j
  f16x8 gwa[4][8];
#pragma unroll
  for (int t = 0; t < 4; ++t) {
#pragma unroll
    for (int cc = 0; cc < 8; ++cc) {
      const float* wp =
          gate_w + (16 * t + c16) * GIN + 256 * w + 32 * cc + 8 * g4;
      uint4 q = make_uint4(pkf16(wp[0], wp[1]), pkf16(wp[2], wp[3]),
                           pkf16(wp[4], wp[5]), pkf16(wp[6], wp[7]));
      gwa[t][cc] = __builtin_bit_cast(f16x8, q);
    }
  }
  const float gb = gate_b[d];

  // ---- per-lane sign masks for k=cq (i-indexed) ----
  u32 sb[NBL];
#pragma unroll
  for (int i = 0; i < NBL; ++i)
    sb[i] = gp_negbit(i, i ^ cq) ? 0x80000000u : 0u;
  __syncthreads();

  // per-lane copies selected per step by uniform xi (R3/R5-verified)
  const float rcv0 = rc[0][d] + gb, rcv1 = rc[1][d] + gb;
  const float rcv2 = rc[2][d] + gb, rcv3 = rc[3][d] + gb;
  const float iv0 = inv_lds[0], iv1 = inv_lds[1];
  const float iv2 = inv_lds[2], iv3 = inv_lds[3];

  // register-resident own quad: u_j = h[d][cq + 8j]
  float u0 = (cq == 0) ? 1.f : 0.f, u1 = 0.f, u2 = 0.f, u3 = 0.f;

  // ---- software-pipelined scalar loads of x / raw emb rows (R3) ----
  const int* xg = x + b * TT;
  int xiA = uni_i(xg[0]);
  int xiB = uni_i(xg[1]);
  float rnA[NBL], rnB[NBL];
#pragma unroll
  for (int i = 0; i < NBL; ++i) rnA[i] = uni_f(emb[xiA * NBL + i]);

  for (int t = 0; t < TT; t += 2) {
#pragma unroll
    for (int i = 0; i < NBL; ++i) rnB[i] = uni_f(emb[xiB * NBL + i]);
    int xiC = uni_i(xg[(t + 2 < TT) ? t + 2 : 0]);
    STEP(0, rnA, xiA);
#pragma unroll
    for (int i = 0; i < NBL; ++i) rnA[i] = uni_f(emb[xiC * NBL + i]);
    int xiD = uni_i(xg[(t + 3 < TT) ? t + 3 : 0]);
    STEP(1, rnB, xiB);
    xiA = xiC;
    xiB = xiD;
  }

  // ================= fused head (R5/R10-verified, 512 thr) =================
  {
    float* ho = hs + d * 32 + cq;
    ho[0] = u0;
    ho[8] = u1;
    ho[16] = u2;
    ho[24] = u3;
  }
  __syncthreads();

  const int hr = tid >> 2;  // output row 0..127
  const int seg = tid & 3;  // column segment (512 floats)
  float acc = 0.f;
  {
    const float4* w4 = (const float4*)(w1 + hr * 2048 + seg * 512);
    const float4* h4 = (const float4*)(hs + seg * 512);
#pragma unroll 8
    for (int k = 0; k < 128; ++k) {
      float4 a = w4[k], hv = h4[k];
      acc = fmaf(a.x, hv.x, acc);
      acc = fmaf(a.y, hv.y, acc);
      acc = fmaf(a.z, hv.z, acc);
      acc = fmaf(a.w, hv.w, acc);
    }
  }
  acc = dpp_add_f<0xB1>(acc);
  acc = dpp_add_f<0x4E>(acc);  // all 4 lanes of the quad hold full row dot
  float z = acc + b1g[hr];

  // LayerNorm stats over 128 rows (each row appears in 4 lanes -> /512)
  float s1 = z, s2 = z * z;
  s1 = dpp_add_f<0xB1>(s1); s1 = dpp_add_f<0x4E>(s1);
  s1 = dpp_add_f<0x141>(s1); s1 = dpp_add_f<0x140>(s1);
  s1 = swz_add16(s1); s1 += bpermf(bp32, s1);
  s2 = dpp_add_f<0xB1>(s2); s2 = dpp_add_f<0x4E>(s2);
  s2 = dpp_add_f<0x141>(s2); s2 = dpp_add_f<0x140>(s2);
  s2 = swz_add16(s2); s2 += bpermf(bp32, s2);
  if (l == 0) { redA[w][0] = s1; redA[w][1] = s2; }
  __syncthreads();
  float tot1 = 0.f, tot2 = 0.f;
#pragma unroll
  for (int k = 0; k < 8; ++k) { tot1 += redA[k][0]; tot2 += redA[k][1]; }
  float mu = tot1 * (1.f / 512.f);
  float var = tot2 * (1.f / 512.f) - mu * mu;
  z = (z - mu) * rsqrtf(var + 1e-5f) * ln_g[hr] + ln_b[hr];
  z = fmaxf(z, 0.f);

  float c0 = (seg == 0) ? z * w2[hr] : 0.f;
  float c1 = (seg == 0) ? z * w2[128 + hr] : 0.f;
  c0 = dpp_add_f<0xB1>(c0); c0 = dpp_add_f<0x4E>(c0);
  c0 = dpp_add_f<0x141>(c0); c0 = dpp_add_f<0x140>(c0);
  c0 = swz_add16(c0); c0 += bpermf(bp32, c0);
  c1 = dpp_add_f<0xB1>(c1); c1 = dpp_add_f<0x4E>(c1);
  c1 = dpp_add_f<0x141>(c1); c1 = dpp_add_f<0x140>(c1);
  c1 = swz_add16(c1); c1 += bpermf(bp32, c1);
  if (l == 0) { redB[w][0] = c0; redB[w][1] = c1; }
  __syncthreads();
  if (tid == 0) {
    float p0 = 0.f, p1 = 0.f;
#pragma unroll
    for (int k = 0; k < 8; ++k) { p0 += redB[k][0]; p1 += redB[k][1]; }
    out[b * 2 + 0] = p0 + b2[0];
    out[b * 2 + 1] = p1 + b2[1];
  }
}

extern "C" void kernel_launch(void* const* d_in, const int* in_sizes, int n_in,
                              void* d_out, int out_size, void* d_ws,
                              size_t ws_size, hipStream_t stream) {
  (void)in_sizes; (void)n_in; (void)out_size; (void)d_ws; (void)ws_size;
  const int* x = (const int*)d_in[0];
  const float* emb = (const float*)d_in[1];
  const float* gate_w = (const float*)d_in[2];
  const float* gate_b = (const float*)d_in[3];
  const float* w1 = (const float*)d_in[4];
  const float* b1 = (const float*)d_in[5];
  const float* ln_g = (const float*)d_in[6];
  const float* ln_b = (const float*)d_in[7];
  const float* w2 = (const float*)d_in[8];
  const float* b2 = (const float*)d_in[9];
  float* out = (float*)d_out;

  versor_fused<<<dim3(BB), dim3(512), 0, stream>>>(
      x, emb, gate_w, gate_b, w1, b1, ln_g, ln_b, w2, b2, out);
}